// Round 1
// baseline (1565.201 us; speedup 1.0000x reference)
//
#include <hip/hip_runtime.h>
#include <hip/hip_bf16.h>

typedef __attribute__((ext_vector_type(8))) short bf16x8;
typedef __attribute__((ext_vector_type(4))) float f32x4;
using bf16 = __hip_bfloat16;

#define D_ 1024
#define T_ 2048
#define B_ 4
#define F_ 4096

// ---------------- LayerNorm (fp32 in -> bf16 out), one block per row ----------------
__global__ __launch_bounds__(256) void ln_kernel(
    const float* __restrict__ x, const float* __restrict__ g,
    const float* __restrict__ b, bf16* __restrict__ out)
{
  int row = blockIdx.x;
  int tid = threadIdx.x;
  const float4 v = *reinterpret_cast<const float4*>(x + (size_t)row * D_ + tid * 4);
  float s = v.x + v.y + v.z + v.w;
  float q = v.x * v.x + v.y * v.y + v.z * v.z + v.w * v.w;
#pragma unroll
  for (int off = 32; off > 0; off >>= 1) {
    s += __shfl_down(s, off);
    q += __shfl_down(q, off);
  }
  __shared__ float psum[4], psq[4], stats[2];
  if ((tid & 63) == 0) { psum[tid >> 6] = s; psq[tid >> 6] = q; }
  __syncthreads();
  if (tid == 0) {
    float S = psum[0] + psum[1] + psum[2] + psum[3];
    float Q = psq[0] + psq[1] + psq[2] + psq[3];
    float mu = S * (1.0f / D_);
    float var = Q * (1.0f / D_) - mu * mu;
    stats[0] = mu;
    stats[1] = rsqrtf(var + 1e-5f);
  }
  __syncthreads();
  float mu = stats[0], rv = stats[1];
  const float4 gv = *reinterpret_cast<const float4*>(g + tid * 4);
  const float4 bv = *reinterpret_cast<const float4*>(b + tid * 4);
  bf16 o[4];
  o[0] = __float2bfloat16((v.x - mu) * rv * gv.x + bv.x);
  o[1] = __float2bfloat16((v.y - mu) * rv * gv.y + bv.y);
  o[2] = __float2bfloat16((v.z - mu) * rv * gv.z + bv.z);
  o[3] = __float2bfloat16((v.w - mu) * rv * gv.w + bv.w);
  *reinterpret_cast<ushort4*>(out + (size_t)row * D_ + tid * 4) =
      *reinterpret_cast<ushort4*>(o);
}

// ---------------- Generic 128x128 bf16 MFMA GEMM ----------------
// C[M,N] = A[M,K](bf16) @ B[K,N](TB: float converts on stage, or bf16)
//          (+bias) (+ReLU) (+fp32 residual), out TOUT (bf16 or float).
// grid: (N/128, M/128, batches). 256 threads = 4 waves, each wave does 64x64.
template <typename TB, typename TOUT, bool RELU>
__global__ __launch_bounds__(256) void gemm_kernel(
    const bf16* __restrict__ A, int lda, long strideAb,
    const TB* __restrict__ Bm, int ldb, long strideBb,
    const float* __restrict__ bias,
    const float* __restrict__ resid, int ldr, long strideRb,
    TOUT* __restrict__ Cm, int ldc, long strideCb,
    int M, int N, int K)
{
  __shared__ __align__(16) bf16 As[128][40];  // [m][k], +8 pad
  __shared__ __align__(16) bf16 Bs[128][40];  // [n][k], +8 pad
  const int tid = threadIdx.x;
  const int lane = tid & 63;
  const int w = tid >> 6;
  const int wm = w >> 1, wn = w & 1;
  const int m0 = blockIdx.y * 128;
  const int n0 = blockIdx.x * 128;
  const int bz = blockIdx.z;
  const bf16* Ab = A + (size_t)bz * strideAb;
  const TB* Bb = Bm + (size_t)bz * strideBb;

  f32x4 acc[4][4] = {};

  for (int kt = 0; kt < K; kt += 32) {
    // stage A: 128 rows x 32 cols bf16 (512 chunks of 8 bf16)
#pragma unroll
    for (int t = 0; t < 2; ++t) {
      int cid = t * 256 + tid;
      int r = cid >> 2;
      int ko = (cid & 3) * 8;
      *reinterpret_cast<uint4*>(&As[r][ko]) =
          *reinterpret_cast<const uint4*>(Ab + (size_t)(m0 + r) * lda + kt + ko);
    }
    // stage B transposed into [n][k]
    if constexpr (sizeof(TB) == 4) {
#pragma unroll
      for (int t = 0; t < 4; ++t) {
        int sidx = t * 256 + tid;
        int k = sidx >> 5;
        int nq = sidx & 31;
        const float4 f = *reinterpret_cast<const float4*>(
            (const float*)Bb + (size_t)(kt + k) * ldb + n0 + nq * 4);
        Bs[nq * 4 + 0][k] = __float2bfloat16(f.x);
        Bs[nq * 4 + 1][k] = __float2bfloat16(f.y);
        Bs[nq * 4 + 2][k] = __float2bfloat16(f.z);
        Bs[nq * 4 + 3][k] = __float2bfloat16(f.w);
      }
    } else {
#pragma unroll
      for (int t = 0; t < 2; ++t) {
        int sidx = t * 256 + tid;
        int k = sidx >> 4;
        int nq = sidx & 15;
        const bf16* src = (const bf16*)Bb + (size_t)(kt + k) * ldb + n0 + nq * 8;
        bf16 tmp[8];
        *reinterpret_cast<uint4*>(tmp) = *reinterpret_cast<const uint4*>(src);
#pragma unroll
        for (int j = 0; j < 8; ++j) Bs[nq * 8 + j][k] = tmp[j];
      }
    }
    __syncthreads();

    const int krd = (lane >> 4) * 8;
    bf16x8 aF[4], bF[4];
#pragma unroll
    for (int m = 0; m < 4; ++m)
      aF[m] = *reinterpret_cast<const bf16x8*>(&As[wm * 64 + m * 16 + (lane & 15)][krd]);
#pragma unroll
    for (int n = 0; n < 4; ++n)
      bF[n] = *reinterpret_cast<const bf16x8*>(&Bs[wn * 64 + n * 16 + (lane & 15)][krd]);
#pragma unroll
    for (int m = 0; m < 4; ++m)
#pragma unroll
      for (int n = 0; n < 4; ++n)
        acc[m][n] = __builtin_amdgcn_mfma_f32_16x16x32_bf16(aF[m], bF[n], acc[m][n], 0, 0, 0);
    __syncthreads();
  }

  const float* Rb = resid ? resid + (size_t)bz * strideRb : nullptr;
  TOUT* Cb = Cm + (size_t)bz * strideCb;
#pragma unroll
  for (int n = 0; n < 4; ++n) {
    int gc = n0 + wn * 64 + n * 16 + (lane & 15);
    float bv = bias ? bias[gc] : 0.0f;
#pragma unroll
    for (int m = 0; m < 4; ++m) {
      int gr = m0 + wm * 64 + m * 16 + ((lane >> 4) << 2);
#pragma unroll
      for (int j = 0; j < 4; ++j) {
        float v = acc[m][n][j] + bv;
        if (RELU) v = fmaxf(v, 0.0f);
        int row = gr + j;
        if (Rb) v += Rb[(size_t)row * ldr + gc];
        if constexpr (sizeof(TOUT) == 2)
          Cb[(size_t)row * ldc + gc] = __float2bfloat16(v);
        else
          Cb[(size_t)row * ldc + gc] = v;
      }
    }
  }
}

// ---------------- Attention scores + causal softmax -> P (bf16) ----------------
// One block per (batch, 16 q-rows). Q frags in registers, K streamed from global,
// S row-block in LDS, wave-parallel softmax, writes normalized P row (zeros above diag).
__global__ __launch_bounds__(256) void attn_scores_kernel(
    const bf16* __restrict__ qkv, bf16* __restrict__ P)
{
  __shared__ float Ss[16][T_];  // 128 KB
  const int qb = blockIdx.x;    // 0..127
  const int b = blockIdx.z;
  const int t0 = qb * 16;
  const int tid = threadIdx.x;
  const int lane = tid & 63;
  const int w = tid >> 6;

  // preload Q fragments: row = t0 + (lane&15), k-chunks of 32 over C=1024
  const bf16* qbase = qkv + ((size_t)(b * T_ + t0 + (lane & 15))) * 3072 + ((lane >> 4) * 8);
  bf16x8 qF[32];
#pragma unroll
  for (int ck = 0; ck < 32; ++ck)
    qF[ck] = *reinterpret_cast<const bf16x8*>(qbase + ck * 32);

  for (int sc = w; sc <= qb; sc += 4) {
    int s0 = sc * 16;
    const bf16* kbase =
        qkv + ((size_t)(b * T_ + s0 + (lane & 15))) * 3072 + D_ + ((lane >> 4) * 8);
    f32x4 acc = {0.f, 0.f, 0.f, 0.f};
#pragma unroll
    for (int ck = 0; ck < 32; ++ck) {
      bf16x8 kF = *reinterpret_cast<const bf16x8*>(kbase + ck * 32);
      acc = __builtin_amdgcn_mfma_f32_16x16x32_bf16(qF[ck], kF, acc, 0, 0, 0);
    }
    int s = s0 + (lane & 15);
#pragma unroll
    for (int j = 0; j < 4; ++j) {
      int r = ((lane >> 4) << 2) + j;
      if (s <= t0 + r) Ss[r][s] = acc[j] * 0.03125f;  // 1/sqrt(1024)
    }
  }
  __syncthreads();

  // softmax: 16 threads per row
  const int r = tid >> 4;
  const int l16 = tid & 15;
  const int t = t0 + r;
  float mx = -1e30f;
  for (int s = l16; s <= t; s += 16) mx = fmaxf(mx, Ss[r][s]);
#pragma unroll
  for (int off = 8; off > 0; off >>= 1) mx = fmaxf(mx, __shfl_xor(mx, off, 16));
  float sum = 0.f;
  for (int s = l16; s <= t; s += 16) {
    float e = __expf(Ss[r][s] - mx);
    Ss[r][s] = e;
    sum += e;
  }
#pragma unroll
  for (int off = 8; off > 0; off >>= 1) sum += __shfl_xor(sum, off, 16);
  const float inv = 1.0f / sum;
  bf16* Prow = P + ((size_t)b * T_ + t) * T_;
  for (int s = l16; s < T_; s += 16) {
    float v = (s <= t) ? Ss[r][s] * inv : 0.0f;
    Prow[s] = __float2bfloat16(v);
  }
}

// ---------------- launch ----------------
extern "C" void kernel_launch(void* const* d_in, const int* in_sizes, int n_in,
                              void* d_out, int out_size, void* d_ws, size_t ws_size,
                              hipStream_t stream)
{
  const float* x      = (const float*)d_in[0];
  const float* ln1_g  = (const float*)d_in[1];
  const float* ln1_b  = (const float*)d_in[2];
  const float* qkv_w  = (const float*)d_in[3];
  const float* qkv_b  = (const float*)d_in[4];
  const float* proj_w = (const float*)d_in[5];
  const float* proj_b = (const float*)d_in[6];
  const float* ln2_g  = (const float*)d_in[7];
  const float* ln2_b  = (const float*)d_in[8];
  const float* ff1_w  = (const float*)d_in[9];
  const float* ff1_b  = (const float*)d_in[10];
  const float* ff2_w  = (const float*)d_in[11];
  const float* ff2_b  = (const float*)d_in[12];
  float* out = (float*)d_out;

  // workspace layout (liveness-based reuse), total 128 MB:
  //  [0,48M)    qkv bf16 (dead after PV)     -> reused by ff1 out (64MB, [0,64M))
  //  [48M,80M)  P bf16   (dead after PV)
  //  [80M,96M)  r1 bf16: h -> y -> h2 (16MB)
  //  [96M,128M) x2 fp32 (32MB)
  char* ws = (char*)d_ws;
  bf16* qkvb = (bf16*)(ws);
  bf16* Pbuf = (bf16*)(ws + 50331648L);
  bf16* r1   = (bf16*)(ws + 83886080L);
  float* x2  = (float*)(ws + 100663296L);
  bf16* ff1o = (bf16*)(ws);

  const int R = B_ * T_;  // 8192 rows

  // h = LN1(x)
  ln_kernel<<<dim3(R), 256, 0, stream>>>(x, ln1_g, ln1_b, r1);
  // qkv = h @ qkv_w + qkv_b
  gemm_kernel<float, bf16, false><<<dim3(3 * D_ / 128, R / 128, 1), 256, 0, stream>>>(
      r1, D_, 0, qkv_w, 3 * D_, 0, qkv_b, nullptr, 0, 0, qkvb, 3 * D_, 0, R, 3 * D_, D_);
  // P = softmax(mask(q k^T / 32))
  attn_scores_kernel<<<dim3(T_ / 16, 1, B_), 256, 0, stream>>>(qkvb, Pbuf);
  // y = P @ v
  gemm_kernel<bf16, bf16, false><<<dim3(D_ / 128, T_ / 128, B_), 256, 0, stream>>>(
      Pbuf, T_, (long)T_ * T_, qkvb + 2 * D_, 3 * D_, (long)T_ * 3 * D_,
      nullptr, nullptr, 0, 0, r1, D_, (long)T_ * D_, T_, D_, T_);
  // x2 = x + y @ proj_w + proj_b
  gemm_kernel<float, float, false><<<dim3(D_ / 128, R / 128, 1), 256, 0, stream>>>(
      r1, D_, 0, proj_w, D_, 0, proj_b, x, D_, 0, x2, D_, 0, R, D_, D_);
  // h2 = LN2(x2)
  ln_kernel<<<dim3(R), 256, 0, stream>>>(x2, ln2_g, ln2_b, r1);
  // f = relu(h2 @ ff1_w + ff1_b)
  gemm_kernel<float, bf16, true><<<dim3(F_ / 128, R / 128, 1), 256, 0, stream>>>(
      r1, D_, 0, ff1_w, F_, 0, ff1_b, nullptr, 0, 0, ff1o, F_, 0, R, F_, D_);
  // out = x2 + f @ ff2_w + ff2_b
  gemm_kernel<float, float, false><<<dim3(D_ / 128, R / 128, 1), 256, 0, stream>>>(
      ff1o, F_, 0, ff2_w, D_, 0, ff2_b, x2, D_, 0, out, D_, 0, R, D_, F_);
}

// Round 2
// 879.816 us; speedup vs baseline: 1.7790x; 1.7790x over previous
//
#include <hip/hip_runtime.h>
#include <hip/hip_bf16.h>

typedef __attribute__((ext_vector_type(8))) short bf16x8;
typedef __attribute__((ext_vector_type(4))) float f32x4;
using bf16 = __hip_bfloat16;

#define D_ 1024
#define T_ 2048
#define B_ 4
#define F_ 4096

__device__ __forceinline__ void gload_lds16(const void* g, void* l) {
  __builtin_amdgcn_global_load_lds(
      (const __attribute__((address_space(1))) void*)g,
      (__attribute__((address_space(3))) void*)l, 16, 0, 0);
}

// ---------------- LayerNorm (fp32 in -> bf16 out), one block per row ----------------
__global__ __launch_bounds__(256) void ln_kernel(
    const float* __restrict__ x, const float* __restrict__ g,
    const float* __restrict__ b, bf16* __restrict__ out)
{
  int row = blockIdx.x;
  int tid = threadIdx.x;
  const float4 v = *reinterpret_cast<const float4*>(x + (size_t)row * D_ + tid * 4);
  float s = v.x + v.y + v.z + v.w;
  float q = v.x * v.x + v.y * v.y + v.z * v.z + v.w * v.w;
#pragma unroll
  for (int off = 32; off > 0; off >>= 1) {
    s += __shfl_down(s, off);
    q += __shfl_down(q, off);
  }
  __shared__ float psum[4], psq[4], stats[2];
  if ((tid & 63) == 0) { psum[tid >> 6] = s; psq[tid >> 6] = q; }
  __syncthreads();
  if (tid == 0) {
    float S = psum[0] + psum[1] + psum[2] + psum[3];
    float Q = psq[0] + psq[1] + psq[2] + psq[3];
    float mu = S * (1.0f / D_);
    float var = Q * (1.0f / D_) - mu * mu;
    stats[0] = mu;
    stats[1] = rsqrtf(var + 1e-5f);
  }
  __syncthreads();
  float mu = stats[0], rv = stats[1];
  const float4 gv = *reinterpret_cast<const float4*>(g + tid * 4);
  const float4 bv = *reinterpret_cast<const float4*>(b + tid * 4);
  bf16 o[4];
  o[0] = __float2bfloat16((v.x - mu) * rv * gv.x + bv.x);
  o[1] = __float2bfloat16((v.y - mu) * rv * gv.y + bv.y);
  o[2] = __float2bfloat16((v.z - mu) * rv * gv.z + bv.z);
  o[3] = __float2bfloat16((v.w - mu) * rv * gv.w + bv.w);
  *reinterpret_cast<ushort4*>(out + (size_t)row * D_ + tid * 4) =
      *reinterpret_cast<ushort4*>(o);
}

// ---------------- Transpose fp32 [R][C] -> bf16 [C][R] ----------------
__global__ __launch_bounds__(256) void transpose_w_kernel(
    const float* __restrict__ in, bf16* __restrict__ out, int R, int C)
{
  __shared__ float t[32][33];
  int c0 = blockIdx.x * 32, r0 = blockIdx.y * 32;
  int c = threadIdx.x & 31, r8 = threadIdx.x >> 5;
#pragma unroll
  for (int i = 0; i < 4; ++i)
    t[r8 + i * 8][c] = in[(size_t)(r0 + r8 + i * 8) * C + c0 + c];
  __syncthreads();
#pragma unroll
  for (int i = 0; i < 4; ++i)
    out[(size_t)(c0 + r8 + i * 8) * R + r0 + c] = __float2bfloat16(t[c][r8 + i * 8]);
}

// ---------------- Transpose V (bf16 strided) -> VT [D][T] per batch ----------------
__global__ __launch_bounds__(256) void transpose_v_kernel(
    const bf16* __restrict__ qkv, bf16* __restrict__ vt)
{
  __shared__ bf16 t[32][34];
  int b = blockIdx.z;
  int c0 = blockIdx.x * 32;  // channel
  int r0 = blockIdx.y * 32;  // token
  const bf16* in = qkv + (size_t)b * T_ * 3072 + 2 * D_;
  bf16* out = vt + (size_t)b * D_ * T_;
  int c = threadIdx.x & 31, r8 = threadIdx.x >> 5;
#pragma unroll
  for (int i = 0; i < 4; ++i)
    t[r8 + i * 8][c] = in[(size_t)(r0 + r8 + i * 8) * 3072 + c0 + c];
  __syncthreads();
#pragma unroll
  for (int i = 0; i < 4; ++i)
    out[(size_t)(c0 + r8 + i * 8) * T_ + r0 + c] = t[c][r8 + i * 8];
}

// ---------------- m97-structure GEMM: C = A[M,K] @ Bt[N,K]^T ----------------
// A, Bt bf16; stage via global_load_lds width 16; 128x128 tile, BK=32, 4 waves.
template <typename TOUT, bool RELU>
__global__ __launch_bounds__(256) void gemm_bt_kernel(
    const bf16* __restrict__ A, int lda, long sAb,
    const bf16* __restrict__ Bt, int ldb, long sBb,
    const float* __restrict__ bias,
    const float* __restrict__ resid, int ldr, long sRb,
    TOUT* __restrict__ C, int ldc, long sCb,
    int K)
{
  __shared__ __align__(16) bf16 As[128 * 32];
  __shared__ __align__(16) bf16 Bs[128 * 32];
  const int tid = threadIdx.x;
  const int lane = tid & 63;
  const int w = __builtin_amdgcn_readfirstlane(tid >> 6);
  const int wm = w >> 1, wn = w & 1;
  const int m0 = blockIdx.y * 128, n0 = blockIdx.x * 128;
  const bf16* Ab = A + (size_t)blockIdx.z * sAb;
  const bf16* Bb = Bt + (size_t)blockIdx.z * sBb;

  const int srow = lane >> 2;        // 0..15 row within 16-row chunk
  const int sko = (lane & 3) * 8;    // 0,8,16,24 k-offset (8 bf16 = 16B)

  f32x4 acc[4][4] = {};
  for (int kt = 0; kt < K; kt += 32) {
    __syncthreads();
#pragma unroll
    for (int i = 0; i < 2; ++i) {
      int c = w * 2 + i;  // chunk 0..7, wave-uniform
      gload_lds16(Ab + (size_t)(m0 + c * 16 + srow) * lda + kt + sko, &As[c * 512]);
      gload_lds16(Bb + (size_t)(n0 + c * 16 + srow) * ldb + kt + sko, &Bs[c * 512]);
    }
    __syncthreads();
    const int koff = (lane >> 4) * 8;
    bf16x8 aF[4], bF[4];
#pragma unroll
    for (int m = 0; m < 4; ++m)
      aF[m] = *reinterpret_cast<const bf16x8*>(&As[(wm * 64 + m * 16 + (lane & 15)) * 32 + koff]);
#pragma unroll
    for (int n = 0; n < 4; ++n)
      bF[n] = *reinterpret_cast<const bf16x8*>(&Bs[(wn * 64 + n * 16 + (lane & 15)) * 32 + koff]);
#pragma unroll
    for (int m = 0; m < 4; ++m)
#pragma unroll
      for (int n = 0; n < 4; ++n)
        acc[m][n] = __builtin_amdgcn_mfma_f32_16x16x32_bf16(aF[m], bF[n], acc[m][n], 0, 0, 0);
  }

  const float* Rb = resid ? resid + (size_t)blockIdx.z * sRb : nullptr;
  TOUT* Cb = C + (size_t)blockIdx.z * sCb;
#pragma unroll
  for (int n = 0; n < 4; ++n) {
    int gc = n0 + wn * 64 + n * 16 + (lane & 15);
    float bv = bias ? bias[gc] : 0.0f;
#pragma unroll
    for (int m = 0; m < 4; ++m) {
      int gr = m0 + wm * 64 + m * 16 + ((lane >> 4) << 2);
#pragma unroll
      for (int j = 0; j < 4; ++j) {
        float v = acc[m][n][j] + bv;
        if (RELU) v = fmaxf(v, 0.0f);
        int row = gr + j;
        if (Rb) v += Rb[(size_t)row * ldr + gc];
        if constexpr (sizeof(TOUT) == 2)
          Cb[(size_t)row * ldc + gc] = __float2bfloat16(v);
        else
          Cb[(size_t)row * ldc + gc] = v;
      }
    }
  }
}

// ---------------- Attention scores + causal softmax -> P (bf16) ----------------
__global__ __launch_bounds__(256) void attn_scores_kernel(
    const bf16* __restrict__ qkv, bf16* __restrict__ P)
{
  __shared__ float Ss[16][T_];  // 128 KB
  const int qb = blockIdx.x;    // 0..127
  const int b = blockIdx.z;
  const int t0 = qb * 16;
  const int tid = threadIdx.x;
  const int lane = tid & 63;
  const int w = tid >> 6;

  const bf16* qbase = qkv + ((size_t)(b * T_ + t0 + (lane & 15))) * 3072 + ((lane >> 4) * 8);
  bf16x8 qF[32];
#pragma unroll
  for (int ck = 0; ck < 32; ++ck)
    qF[ck] = *reinterpret_cast<const bf16x8*>(qbase + ck * 32);

  for (int sc = w; sc <= qb; sc += 4) {
    int s0 = sc * 16;
    const bf16* kbase =
        qkv + ((size_t)(b * T_ + s0 + (lane & 15))) * 3072 + D_ + ((lane >> 4) * 8);
    f32x4 acc = {0.f, 0.f, 0.f, 0.f};
#pragma unroll
    for (int ck = 0; ck < 32; ++ck) {
      bf16x8 kF = *reinterpret_cast<const bf16x8*>(kbase + ck * 32);
      acc = __builtin_amdgcn_mfma_f32_16x16x32_bf16(qF[ck], kF, acc, 0, 0, 0);
    }
    int s = s0 + (lane & 15);
#pragma unroll
    for (int j = 0; j < 4; ++j) {
      int r = ((lane >> 4) << 2) + j;
      if (s <= t0 + r) Ss[r][s] = acc[j] * 0.03125f;  // 1/sqrt(1024)
    }
  }
  __syncthreads();

  const int r = tid >> 4;
  const int l16 = tid & 15;
  const int t = t0 + r;
  float mx = -1e30f;
  for (int s = l16; s <= t; s += 16) mx = fmaxf(mx, Ss[r][s]);
#pragma unroll
  for (int off = 8; off > 0; off >>= 1) mx = fmaxf(mx, __shfl_xor(mx, off, 16));
  float sum = 0.f;
  for (int s = l16; s <= t; s += 16) {
    float e = __expf(Ss[r][s] - mx);
    Ss[r][s] = e;
    sum += e;
  }
#pragma unroll
  for (int off = 8; off > 0; off >>= 1) sum += __shfl_xor(sum, off, 16);
  const float inv = 1.0f / sum;
  bf16* Prow = P + ((size_t)b * T_ + t) * T_;
  for (int s = l16; s < T_; s += 16) {
    float v = (s <= t) ? Ss[r][s] * inv : 0.0f;
    Prow[s] = __float2bfloat16(v);
  }
}

// ---------------- launch ----------------
extern "C" void kernel_launch(void* const* d_in, const int* in_sizes, int n_in,
                              void* d_out, int out_size, void* d_ws, size_t ws_size,
                              hipStream_t stream)
{
  const float* x      = (const float*)d_in[0];
  const float* ln1_g  = (const float*)d_in[1];
  const float* ln1_b  = (const float*)d_in[2];
  const float* qkv_w  = (const float*)d_in[3];
  const float* qkv_b  = (const float*)d_in[4];
  const float* proj_w = (const float*)d_in[5];
  const float* proj_b = (const float*)d_in[6];
  const float* ln2_g  = (const float*)d_in[7];
  const float* ln2_b  = (const float*)d_in[8];
  const float* ff1_w  = (const float*)d_in[9];
  const float* ff1_b  = (const float*)d_in[10];
  const float* ff2_w  = (const float*)d_in[11];
  const float* ff2_b  = (const float*)d_in[12];
  float* out = (float*)d_out;

  // workspace layout (128 MB total):
  //  [0,48M)        qkv bf16 (dead after PV)  -> ff1o [0,64M) later
  //  [48M,80M)      P bf16   (dead after PV)
  //  [80M,96M)      r1 bf16: h -> y -> h2
  //  [96M,112M)     VT bf16 (dead after PV)  -> ff1_wT [96M,104M) later
  //  [112M,128M)    qkv_wT(6M) | proj_wT(2M) | ff2_wT(8M)   (live always)
  //  x2 lives in d_out (proj writes it, ff2 reads+overwrites in place)
  char* ws = (char*)d_ws;
  bf16* qkvb    = (bf16*)(ws);
  bf16* Pbuf    = (bf16*)(ws + 50331648L);
  bf16* r1      = (bf16*)(ws + 83886080L);
  bf16* VT      = (bf16*)(ws + 100663296L);
  bf16* ff1_wT  = (bf16*)(ws + 100663296L);
  bf16* qkv_wT  = (bf16*)(ws + 117440512L);
  bf16* proj_wT = (bf16*)(ws + 123731968L);
  bf16* ff2_wT  = (bf16*)(ws + 125829120L);
  bf16* ff1o    = (bf16*)(ws);

  const int R = B_ * T_;  // 8192 rows

  // one-time weight transposes (fp32 [K][N] -> bf16 [N][K])
  transpose_w_kernel<<<dim3(3072 / 32, 1024 / 32), 256, 0, stream>>>(qkv_w, qkv_wT, 1024, 3072);
  transpose_w_kernel<<<dim3(1024 / 32, 1024 / 32), 256, 0, stream>>>(proj_w, proj_wT, 1024, 1024);
  transpose_w_kernel<<<dim3(1024 / 32, 4096 / 32), 256, 0, stream>>>(ff2_w, ff2_wT, 4096, 1024);

  // h = LN1(x)
  ln_kernel<<<dim3(R), 256, 0, stream>>>(x, ln1_g, ln1_b, r1);
  // qkv = h @ qkv_w + qkv_b
  gemm_bt_kernel<bf16, false><<<dim3(3072 / 128, R / 128, 1), 256, 0, stream>>>(
      r1, D_, 0, qkv_wT, D_, 0, qkv_b, nullptr, 0, 0, qkvb, 3072, 0, D_);
  // VT = V^T per batch
  transpose_v_kernel<<<dim3(D_ / 32, T_ / 32, B_), 256, 0, stream>>>(qkvb, VT);
  // P = softmax(mask(q k^T / 32))
  attn_scores_kernel<<<dim3(T_ / 16, 1, B_), 256, 0, stream>>>(qkvb, Pbuf);
  // y = P @ v    (A=P [T,T], Bt=VT [D][T])
  gemm_bt_kernel<bf16, false><<<dim3(D_ / 128, T_ / 128, B_), 256, 0, stream>>>(
      Pbuf, T_, (long)T_ * T_, VT, T_, (long)D_ * T_,
      nullptr, nullptr, 0, 0, r1, D_, (long)T_ * D_, T_);
  // ff1_wT (overwrites VT region, safe after PV)
  transpose_w_kernel<<<dim3(4096 / 32, 1024 / 32), 256, 0, stream>>>(ff1_w, ff1_wT, 1024, 4096);
  // x2 = x + y @ proj_w + proj_b   (into d_out)
  gemm_bt_kernel<float, false><<<dim3(D_ / 128, R / 128, 1), 256, 0, stream>>>(
      r1, D_, 0, proj_wT, D_, 0, proj_b, x, D_, 0, out, D_, 0, D_);
  // h2 = LN2(x2)
  ln_kernel<<<dim3(R), 256, 0, stream>>>(out, ln2_g, ln2_b, r1);
  // f = relu(h2 @ ff1_w + ff1_b)
  gemm_bt_kernel<bf16, true><<<dim3(F_ / 128, R / 128, 1), 256, 0, stream>>>(
      r1, D_, 0, ff1_wT, D_, 0, ff1_b, nullptr, 0, 0, ff1o, F_, 0, D_);
  // out = x2 + f @ ff2_w + ff2_b   (in-place residual on d_out)
  gemm_bt_kernel<float, false><<<dim3(D_ / 128, R / 128, 1), 256, 0, stream>>>(
      ff1o, F_, 0, ff2_wT, F_, 0, ff2_b, out, D_, 0, out, D_, 0, F_);
}

// Round 4
// 629.303 us; speedup vs baseline: 2.4872x; 1.3981x over previous
//
#include <hip/hip_runtime.h>
#include <hip/hip_bf16.h>

typedef __attribute__((ext_vector_type(8))) short bf16x8;
typedef __attribute__((ext_vector_type(4))) float f32x4;
using bf16 = __hip_bfloat16;

#define D_ 1024
#define T_ 2048
#define B_ 4
#define F_ 4096

__device__ __forceinline__ void gload_lds16(const void* g, void* l) {
  __builtin_amdgcn_global_load_lds(
      (const __attribute__((address_space(1))) void*)g,
      (__attribute__((address_space(3))) void*)l, 16, 0, 0);
}

// ---------------- LayerNorm (fp32 in -> bf16 out), one block per row ----------------
__global__ __launch_bounds__(256) void ln_kernel(
    const float* __restrict__ x, const float* __restrict__ g,
    const float* __restrict__ b, bf16* __restrict__ out)
{
  int row = blockIdx.x;
  int tid = threadIdx.x;
  const float4 v = *reinterpret_cast<const float4*>(x + (size_t)row * D_ + tid * 4);
  float s = v.x + v.y + v.z + v.w;
  float q = v.x * v.x + v.y * v.y + v.z * v.z + v.w * v.w;
#pragma unroll
  for (int off = 32; off > 0; off >>= 1) {
    s += __shfl_down(s, off);
    q += __shfl_down(q, off);
  }
  __shared__ float psum[4], psq[4], stats[2];
  if ((tid & 63) == 0) { psum[tid >> 6] = s; psq[tid >> 6] = q; }
  __syncthreads();
  if (tid == 0) {
    float S = psum[0] + psum[1] + psum[2] + psum[3];
    float Q = psq[0] + psq[1] + psq[2] + psq[3];
    float mu = S * (1.0f / D_);
    float var = Q * (1.0f / D_) - mu * mu;
    stats[0] = mu;
    stats[1] = rsqrtf(var + 1e-5f);
  }
  __syncthreads();
  float mu = stats[0], rv = stats[1];
  const float4 gv = *reinterpret_cast<const float4*>(g + tid * 4);
  const float4 bv = *reinterpret_cast<const float4*>(b + tid * 4);
  bf16 o[4];
  o[0] = __float2bfloat16((v.x - mu) * rv * gv.x + bv.x);
  o[1] = __float2bfloat16((v.y - mu) * rv * gv.y + bv.y);
  o[2] = __float2bfloat16((v.z - mu) * rv * gv.z + bv.z);
  o[3] = __float2bfloat16((v.w - mu) * rv * gv.w + bv.w);
  *reinterpret_cast<ushort4*>(out + (size_t)row * D_ + tid * 4) =
      *reinterpret_cast<ushort4*>(o);
}

// ---------------- Transpose fp32 [R][C] -> bf16 [C][R] ----------------
__global__ __launch_bounds__(256) void transpose_w_kernel(
    const float* __restrict__ in, bf16* __restrict__ out, int R, int C)
{
  __shared__ float t[32][33];
  int c0 = blockIdx.x * 32, r0 = blockIdx.y * 32;
  int c = threadIdx.x & 31, r8 = threadIdx.x >> 5;
#pragma unroll
  for (int i = 0; i < 4; ++i)
    t[r8 + i * 8][c] = in[(size_t)(r0 + r8 + i * 8) * C + c0 + c];
  __syncthreads();
#pragma unroll
  for (int i = 0; i < 4; ++i)
    out[(size_t)(c0 + r8 + i * 8) * R + r0 + c] = __float2bfloat16(t[c][r8 + i * 8]);
}

// ---------------- Transpose V (bf16 strided) -> VT [D][T] per batch ----------------
__global__ __launch_bounds__(256) void transpose_v_kernel(
    const bf16* __restrict__ qkv, bf16* __restrict__ vt)
{
  __shared__ bf16 t[32][34];
  int b = blockIdx.z;
  int c0 = blockIdx.x * 32;  // channel
  int r0 = blockIdx.y * 32;  // token
  const bf16* in = qkv + (size_t)b * T_ * 3072 + 2 * D_;
  bf16* out = vt + (size_t)b * D_ * T_;
  int c = threadIdx.x & 31, r8 = threadIdx.x >> 5;
#pragma unroll
  for (int i = 0; i < 4; ++i)
    t[r8 + i * 8][c] = in[(size_t)(r0 + r8 + i * 8) * 3072 + c0 + c];
  __syncthreads();
#pragma unroll
  for (int i = 0; i < 4; ++i)
    out[(size_t)(c0 + r8 + i * 8) * T_ + r0 + c] = t[c][r8 + i * 8];
}

// ---------------- m97-structure GEMM: C = A[M,K] @ Bt[N,K]^T ----------------
// TRI_SKIP: skip tiles above the diagonal (scores GEMM).
// TRI_K:    per-block-row K-cap kmax=(by+1)*128 (causal PV GEMM).
template <typename TOUT, bool RELU, bool TRI_SKIP, bool TRI_K>
__global__ __launch_bounds__(256) void gemm_bt_kernel(
    const bf16* __restrict__ A, int lda, long sAb,
    const bf16* __restrict__ Bt, int ldb, long sBb,
    const float* __restrict__ bias,
    const float* __restrict__ resid, int ldr, long sRb,
    TOUT* __restrict__ C, int ldc, long sCb,
    int K, float oscale)
{
  if (TRI_SKIP && blockIdx.x > blockIdx.y) return;
  __shared__ __align__(16) bf16 As[128 * 32];
  __shared__ __align__(16) bf16 Bs[128 * 32];
  const int tid = threadIdx.x;
  const int lane = tid & 63;
  const int w = __builtin_amdgcn_readfirstlane(tid >> 6);
  const int wm = w >> 1, wn = w & 1;
  const int m0 = blockIdx.y * 128, n0 = blockIdx.x * 128;
  const bf16* Ab = A + (size_t)blockIdx.z * sAb;
  const bf16* Bb = Bt + (size_t)blockIdx.z * sBb;

  const int srow = lane >> 2;        // 0..15 row within 16-row chunk
  const int sko = (lane & 3) * 8;    // 0,8,16,24 k-offset (8 bf16 = 16B)
  const int kmax = TRI_K ? (blockIdx.y + 1) * 128 : K;

  f32x4 acc[4][4] = {};
  for (int kt = 0; kt < kmax; kt += 32) {
    __syncthreads();
#pragma unroll
    for (int i = 0; i < 2; ++i) {
      int c = w * 2 + i;  // chunk 0..7, wave-uniform
      gload_lds16(Ab + (size_t)(m0 + c * 16 + srow) * lda + kt + sko, &As[c * 512]);
      gload_lds16(Bb + (size_t)(n0 + c * 16 + srow) * ldb + kt + sko, &Bs[c * 512]);
    }
    __syncthreads();
    const int koff = (lane >> 4) * 8;
    bf16x8 aF[4], bF[4];
#pragma unroll
    for (int m = 0; m < 4; ++m)
      aF[m] = *reinterpret_cast<const bf16x8*>(&As[(wm * 64 + m * 16 + (lane & 15)) * 32 + koff]);
#pragma unroll
    for (int n = 0; n < 4; ++n)
      bF[n] = *reinterpret_cast<const bf16x8*>(&Bs[(wn * 64 + n * 16 + (lane & 15)) * 32 + koff]);
#pragma unroll
    for (int m = 0; m < 4; ++m)
#pragma unroll
      for (int n = 0; n < 4; ++n)
        acc[m][n] = __builtin_amdgcn_mfma_f32_16x16x32_bf16(aF[m], bF[n], acc[m][n], 0, 0, 0);
  }

  const float* Rb = resid ? resid + (size_t)blockIdx.z * sRb : nullptr;
  TOUT* Cb = C + (size_t)blockIdx.z * sCb;
#pragma unroll
  for (int n = 0; n < 4; ++n) {
    int gc = n0 + wn * 64 + n * 16 + (lane & 15);
    float bv = bias ? bias[gc] : 0.0f;
#pragma unroll
    for (int m = 0; m < 4; ++m) {
      int gr = m0 + wm * 64 + m * 16 + ((lane >> 4) << 2);
#pragma unroll
      for (int j = 0; j < 4; ++j) {
        float v = acc[m][n][j] * oscale + bv;
        if (RELU) v = fmaxf(v, 0.0f);
        int row = gr + j;
        if (Rb) v += Rb[(size_t)row * ldr + gc];
        if constexpr (sizeof(TOUT) == 2)
          Cb[(size_t)row * ldc + gc] = __float2bfloat16(v);
        else
          Cb[(size_t)row * ldc + gc] = v;
      }
    }
  }
}

// ---------------- In-place causal softmax: fp32 S row -> bf16 P row ----------------
// One wave per row. Row t: valid cols 0..t; writes bf16 P at the row start
// (so P has element stride 4096 = 8192B row stride). Cols in [t+1, Keff) get 0;
// cols >= Keff=(t/128+1)*128 are never read downstream (PV caps K per row-block).
__global__ __launch_bounds__(256) void softmax_kernel(float* __restrict__ S)
{
  const int w = threadIdx.x >> 6, lane = threadIdx.x & 63;
  const int t = blockIdx.x * 4 + w;
  const int b = blockIdx.z;
  float* Srow = S + ((size_t)b * T_ + t) * T_;
  const int Keff = ((t >> 7) + 1) << 7;

  float4 vals[8];
  float mx = -1e30f;
#pragma unroll
  for (int c = 0; c < 8; ++c) {
    int col = c * 256 + lane * 4;
    if (col < Keff) {
      vals[c] = *reinterpret_cast<const float4*>(Srow + col);
#pragma unroll
      for (int j = 0; j < 4; ++j)
        if (col + j <= t) mx = fmaxf(mx, ((float*)&vals[c])[j]);
    } else {
      vals[c] = float4{0.f, 0.f, 0.f, 0.f};
    }
  }
#pragma unroll
  for (int off = 32; off > 0; off >>= 1) mx = fmaxf(mx, __shfl_xor(mx, off));

  float sum = 0.f;
#pragma unroll
  for (int c = 0; c < 8; ++c) {
    int col = c * 256 + lane * 4;
#pragma unroll
    for (int j = 0; j < 4; ++j) {
      float e = (col + j <= t) ? __expf(((float*)&vals[c])[j] - mx) : 0.f;
      ((float*)&vals[c])[j] = e;
      sum += e;
    }
  }
#pragma unroll
  for (int off = 32; off > 0; off >>= 1) sum += __shfl_xor(sum, off);
  const float inv = 1.0f / sum;

  bf16* Prow = (bf16*)Srow;
#pragma unroll
  for (int c = 0; c < 8; ++c) {
    int col = c * 256 + lane * 4;
    if (col < Keff) {
      bf16 o[4];
#pragma unroll
      for (int j = 0; j < 4; ++j) o[j] = __float2bfloat16(((float*)&vals[c])[j] * inv);
      *reinterpret_cast<ushort4*>(Prow + col) = *reinterpret_cast<ushort4*>(o);
    }
  }
}

// ---------------- launch ----------------
extern "C" void kernel_launch(void* const* d_in, const int* in_sizes, int n_in,
                              void* d_out, int out_size, void* d_ws, size_t ws_size,
                              hipStream_t stream)
{
  const float* x      = (const float*)d_in[0];
  const float* ln1_g  = (const float*)d_in[1];
  const float* ln1_b  = (const float*)d_in[2];
  const float* qkv_w  = (const float*)d_in[3];
  const float* qkv_b  = (const float*)d_in[4];
  const float* proj_w = (const float*)d_in[5];
  const float* proj_b = (const float*)d_in[6];
  const float* ln2_g  = (const float*)d_in[7];
  const float* ln2_b  = (const float*)d_in[8];
  const float* ff1_w  = (const float*)d_in[9];
  const float* ff1_b  = (const float*)d_in[10];
  const float* ff2_w  = (const float*)d_in[11];
  const float* ff2_b  = (const float*)d_in[12];
  float* out = (float*)d_out;

  // workspace layout (128 MB, liveness-planned):
  //  [0,48M)   qkvb bf16        (dead after scores)  -> y [0,16M), wT [16,34M), h2 [34,50M)
  //  [48,64M)  h bf16 (LN1 out) (dead after QKV)     -> VT [48,64M) (dead after PV)
  //  [64,128M) qkv_wT [64,70M)  (dead after QKV)     -> S fp32/P bf16 -> ff1o [64,128M)
  //  x2 lives in d_out (proj writes, ff2 reads + overwrites in place)
  char* ws = (char*)d_ws;
  bf16*  qkvb    = (bf16*)(ws);
  bf16*  y       = (bf16*)(ws);
  bf16*  proj_wT = (bf16*)(ws + 16777216L);
  bf16*  ff1_wT  = (bf16*)(ws + 18874368L);
  bf16*  ff2_wT  = (bf16*)(ws + 27262976L);
  bf16*  h2      = (bf16*)(ws + 35651584L);
  bf16*  h       = (bf16*)(ws + 50331648L);
  bf16*  VT      = (bf16*)(ws + 50331648L);
  bf16*  qkv_wT  = (bf16*)(ws + 67108864L);
  float* Sbuf    = (float*)(ws + 67108864L);
  bf16*  Pbuf    = (bf16*)(ws + 67108864L);  // in-place, lda=4096
  bf16*  ff1o    = (bf16*)(ws + 67108864L);

  const int R = B_ * T_;  // 8192 rows

  // qkv_wT = bf16(qkv_w)^T
  transpose_w_kernel<<<dim3(3072 / 32, 1024 / 32), 256, 0, stream>>>(qkv_w, qkv_wT, 1024, 3072);
  // h = LN1(x)
  ln_kernel<<<dim3(R), 256, 0, stream>>>(x, ln1_g, ln1_b, h);
  // qkv = h @ qkv_w + qkv_b
  gemm_bt_kernel<bf16, false, false, false><<<dim3(3072 / 128, R / 128, 1), 256, 0, stream>>>(
      h, D_, 0, qkv_wT, D_, 0, qkv_b, nullptr, 0, 0, qkvb, 3072, 0, D_, 1.0f);
  // VT = V^T per batch
  transpose_v_kernel<<<dim3(D_ / 32, T_ / 32, B_), 256, 0, stream>>>(qkvb, VT);
  // S = (Q K^T)/32, lower-triangular 128x128 tiles only, fp32
  gemm_bt_kernel<float, false, true, false><<<dim3(T_ / 128, T_ / 128, B_), 256, 0, stream>>>(
      qkvb, 3072, (long)T_ * 3072, qkvb + D_, 3072, (long)T_ * 3072,
      nullptr, nullptr, 0, 0, Sbuf, T_, (long)T_ * T_, D_, 0.03125f);
  // P = softmax(S) in place (bf16, lda=4096)
  softmax_kernel<<<dim3(T_ / 4, 1, B_), 256, 0, stream>>>(Sbuf);
  // weight transposes into dead qkvb region
  transpose_w_kernel<<<dim3(1024 / 32, 1024 / 32), 256, 0, stream>>>(proj_w, proj_wT, 1024, 1024);
  transpose_w_kernel<<<dim3(4096 / 32, 1024 / 32), 256, 0, stream>>>(ff1_w, ff1_wT, 1024, 4096);
  transpose_w_kernel<<<dim3(1024 / 32, 4096 / 32), 256, 0, stream>>>(ff2_w, ff2_wT, 4096, 1024);
  // y = P @ V   (A=P lda 4096, K capped per row-block by causality)
  gemm_bt_kernel<bf16, false, false, true><<<dim3(D_ / 128, T_ / 128, B_), 256, 0, stream>>>(
      Pbuf, 4096, (long)T_ * 4096, VT, T_, (long)D_ * T_,
      nullptr, nullptr, 0, 0, y, D_, (long)T_ * D_, T_, 1.0f);
  // x2 = x + y @ proj_w + proj_b   (into d_out)
  gemm_bt_kernel<float, false, false, false><<<dim3(D_ / 128, R / 128, 1), 256, 0, stream>>>(
      y, D_, 0, proj_wT, D_, 0, proj_b, x, D_, 0, out, D_, 0, D_, 1.0f);
  // h2 = LN2(x2)
  ln_kernel<<<dim3(R), 256, 0, stream>>>(out, ln2_g, ln2_b, h2);
  // f = relu(h2 @ ff1_w + ff1_b)
  gemm_bt_kernel<bf16, true, false, false><<<dim3(F_ / 128, R / 128, 1), 256, 0, stream>>>(
      h2, D_, 0, ff1_wT, D_, 0, ff1_b, nullptr, 0, 0, ff1o, F_, 0, D_, 1.0f);
  // out = x2 + f @ ff2_w + ff2_b   (in-place residual on d_out)
  gemm_bt_kernel<float, false, false, false><<<dim3(D_ / 128, R / 128, 1), 256, 0, stream>>>(
      ff1o, F_, 0, ff2_wT, F_, 0, ff2_b, out, D_, 0, out, D_, 0, F_, 1.0f);
}

// Round 5
// 597.291 us; speedup vs baseline: 2.6205x; 1.0536x over previous
//
#include <hip/hip_runtime.h>
#include <hip/hip_bf16.h>

typedef __attribute__((ext_vector_type(8))) short bf16x8;
typedef __attribute__((ext_vector_type(4))) float f32x4;
using bf16 = __hip_bfloat16;

#define D_ 1024
#define T_ 2048
#define B_ 4
#define F_ 4096

__device__ __forceinline__ void gload_lds16(const void* g, void* l) {
  __builtin_amdgcn_global_load_lds(
      (const __attribute__((address_space(1))) void*)g,
      (__attribute__((address_space(3))) void*)l, 16, 0, 0);
}

// ---------------- LayerNorm (fp32 in -> bf16 out), one block per row ----------------
__global__ __launch_bounds__(256) void ln_kernel(
    const float* __restrict__ x, const float* __restrict__ g,
    const float* __restrict__ b, bf16* __restrict__ out)
{
  int row = blockIdx.x;
  int tid = threadIdx.x;
  const float4 v = *reinterpret_cast<const float4*>(x + (size_t)row * D_ + tid * 4);
  float s = v.x + v.y + v.z + v.w;
  float q = v.x * v.x + v.y * v.y + v.z * v.z + v.w * v.w;
#pragma unroll
  for (int off = 32; off > 0; off >>= 1) {
    s += __shfl_down(s, off);
    q += __shfl_down(q, off);
  }
  __shared__ float psum[4], psq[4], stats[2];
  if ((tid & 63) == 0) { psum[tid >> 6] = s; psq[tid >> 6] = q; }
  __syncthreads();
  if (tid == 0) {
    float S = psum[0] + psum[1] + psum[2] + psum[3];
    float Q = psq[0] + psq[1] + psq[2] + psq[3];
    float mu = S * (1.0f / D_);
    float var = Q * (1.0f / D_) - mu * mu;
    stats[0] = mu;
    stats[1] = rsqrtf(var + 1e-5f);
  }
  __syncthreads();
  float mu = stats[0], rv = stats[1];
  const float4 gv = *reinterpret_cast<const float4*>(g + tid * 4);
  const float4 bv = *reinterpret_cast<const float4*>(b + tid * 4);
  bf16 o[4];
  o[0] = __float2bfloat16((v.x - mu) * rv * gv.x + bv.x);
  o[1] = __float2bfloat16((v.y - mu) * rv * gv.y + bv.y);
  o[2] = __float2bfloat16((v.z - mu) * rv * gv.z + bv.z);
  o[3] = __float2bfloat16((v.w - mu) * rv * gv.w + bv.w);
  *reinterpret_cast<ushort4*>(out + (size_t)row * D_ + tid * 4) =
      *reinterpret_cast<ushort4*>(o);
}

// ---------------- Transpose fp32 [R][C] -> bf16 [C][R] ----------------
__global__ __launch_bounds__(256) void transpose_w_kernel(
    const float* __restrict__ in, bf16* __restrict__ out, int R, int C)
{
  __shared__ float t[32][33];
  int c0 = blockIdx.x * 32, r0 = blockIdx.y * 32;
  int c = threadIdx.x & 31, r8 = threadIdx.x >> 5;
#pragma unroll
  for (int i = 0; i < 4; ++i)
    t[r8 + i * 8][c] = in[(size_t)(r0 + r8 + i * 8) * C + c0 + c];
  __syncthreads();
#pragma unroll
  for (int i = 0; i < 4; ++i)
    out[(size_t)(c0 + r8 + i * 8) * R + r0 + c] = __float2bfloat16(t[c][r8 + i * 8]);
}

// ---------------- Transpose V (bf16 strided) -> VT [D][T] per batch ----------------
__global__ __launch_bounds__(256) void transpose_v_kernel(
    const bf16* __restrict__ qkv, bf16* __restrict__ vt)
{
  __shared__ bf16 t[32][34];
  int b = blockIdx.z;
  int c0 = blockIdx.x * 32;  // channel
  int r0 = blockIdx.y * 32;  // token
  const bf16* in = qkv + (size_t)b * T_ * 3072 + 2 * D_;
  bf16* out = vt + (size_t)b * D_ * T_;
  int c = threadIdx.x & 31, r8 = threadIdx.x >> 5;
#pragma unroll
  for (int i = 0; i < 4; ++i)
    t[r8 + i * 8][c] = in[(size_t)(r0 + r8 + i * 8) * 3072 + c0 + c];
  __syncthreads();
#pragma unroll
  for (int i = 0; i < 4; ++i)
    out[(size_t)(c0 + r8 + i * 8) * T_ + r0 + c] = t[c][r8 + i * 8];
}

// ============ 256-row tile, BK=64, 8-wave, dbuf + counted-vmcnt GEMM ============
// C[M,N] = A[M,K] @ Bt[N,K]^T (+bias)(+ReLU)(+fp32 resid). BN = 64*NFRAG (256 or 128).
// LDS XOR-swizzle ((row&7)<<4) applied on BOTH sides: staging pre-swizzles the
// per-lane GLOBAL source k-offset (gload_lds dest is linear); reads swizzle back.
// Pipeline: stage t+2 into buf[t&1] only after the barrier ending tile t's reads;
// per-wave vmcnt(LPS) before the barrier guarantees tile t landed. Never vmcnt(0)
// until the final tile.
template <int NFRAG, typename TOUT, bool RELU>
__global__ __launch_bounds__(512) void gemm256_kernel(
    const bf16* __restrict__ A, int lda,
    const bf16* __restrict__ Bt, int ldb,
    const float* __restrict__ bias,
    const float* __restrict__ resid, int ldr,
    TOUT* __restrict__ C, int ldc,
    int K)
{
  constexpr int BN = 64 * NFRAG;            // 256 or 128
  constexpr int BBYTES = BN * 128;          // B tile bytes (rows x 128B)
  constexpr int BCHW = BN / 64;             // B chunks per wave (4 or 2)
  __shared__ __align__(16) char lds[2 * (32768 + BBYTES)];

  const int tid = threadIdx.x;
  const int lane = tid & 63;
  const int w = __builtin_amdgcn_readfirstlane(tid >> 6);
  const int wm = w >> 2;                    // 0..1
  const int wn = w & 3;                     // 0..3
  const int m0 = blockIdx.y * 256, n0 = blockIdx.x * BN;

  // staging: chunk = 8 rows x 128B; lane covers 16B; pre-swizzled source k-byte
  const int srow8 = lane >> 3;                       // row within chunk
  const int skb = ((lane & 7) ^ srow8) * 16;         // swizzled k-byte (0..127)

  const char* Ag = (const char*)A;
  const char* Bg = (const char*)Bt;
  const long ldab = (long)lda * 2, ldbb = (long)ldb * 2;
  const int nt = K >> 6;

  auto stage = [&](int bi, int t) {
    char* base = lds + bi * (32768 + BBYTES);
    long kt2 = (long)t * 128;
#pragma unroll
    for (int i = 0; i < 4; ++i) {
      int c = w * 4 + i;                             // A chunk 0..31
      gload_lds16(Ag + (size_t)(m0 + c * 8 + srow8) * ldab + kt2 + skb,
                  base + c * 1024);
    }
#pragma unroll
    for (int i = 0; i < BCHW; ++i) {
      int c = w * BCHW + i;                          // B chunk
      gload_lds16(Bg + (size_t)(n0 + c * 8 + srow8) * ldbb + kt2 + skb,
                  base + 32768 + c * 1024);
    }
  };

  stage(0, 0);
  stage(1, 1);

  f32x4 acc[8][NFRAG] = {};

  for (int t = 0; t < nt; ++t) {
    if (t < nt - 1) {
      if constexpr (NFRAG == 4) asm volatile("s_waitcnt vmcnt(8)" ::: "memory");
      else                      asm volatile("s_waitcnt vmcnt(6)" ::: "memory");
    } else {
      asm volatile("s_waitcnt vmcnt(0)" ::: "memory");
    }
    __builtin_amdgcn_s_barrier();
    asm volatile("" ::: "memory");

    const char* Ab = lds + (t & 1) * (32768 + BBYTES);
    const char* Bb = Ab + 32768;
    const int l15 = lane & 15;
    const int kbb = (lane >> 4) * 16;

#pragma unroll
    for (int mh = 0; mh < 2; ++mh) {
      bf16x8 aF[4][2];
#pragma unroll
      for (int mi = 0; mi < 4; ++mi)
#pragma unroll
        for (int ks = 0; ks < 2; ++ks) {
          int row = wm * 128 + mh * 64 + mi * 16 + l15;
          int kb = ks * 64 + kbb;
          aF[mi][ks] = *reinterpret_cast<const bf16x8*>(
              Ab + row * 128 + (kb ^ ((row & 7) << 4)));
        }
#pragma unroll
      for (int nh = 0; nh < (NFRAG / 2); ++nh) {
        bf16x8 bF[2][2];
#pragma unroll
        for (int ni = 0; ni < 2; ++ni)
#pragma unroll
          for (int ks = 0; ks < 2; ++ks) {
            int row = wn * (NFRAG * 16) + nh * 32 + ni * 16 + l15;
            int kb = ks * 64 + kbb;
            bF[ni][ks] = *reinterpret_cast<const bf16x8*>(
                Bb + row * 128 + (kb ^ ((row & 7) << 4)));
          }
        __builtin_amdgcn_s_setprio(1);
#pragma unroll
        for (int mi = 0; mi < 4; ++mi)
#pragma unroll
          for (int ni = 0; ni < 2; ++ni)
#pragma unroll
            for (int ks = 0; ks < 2; ++ks)
              acc[mh * 4 + mi][nh * 2 + ni] = __builtin_amdgcn_mfma_f32_16x16x32_bf16(
                  aF[mi][ks], bF[ni][ks], acc[mh * 4 + mi][nh * 2 + ni], 0, 0, 0);
        __builtin_amdgcn_s_setprio(0);
      }
    }
    __builtin_amdgcn_s_barrier();
    asm volatile("" ::: "memory");
    if (t + 2 < nt) stage(t & 1, t + 2);
  }

#pragma unroll
  for (int nf = 0; nf < NFRAG; ++nf) {
    int gc = n0 + wn * (NFRAG * 16) + nf * 16 + (lane & 15);
    float bv = bias ? bias[gc] : 0.0f;
#pragma unroll
    for (int mf = 0; mf < 8; ++mf) {
      int gr = m0 + wm * 128 + mf * 16 + ((lane >> 4) << 2);
#pragma unroll
      for (int j = 0; j < 4; ++j) {
        float v = acc[mf][nf][j] + bv;
        if (RELU) v = fmaxf(v, 0.0f);
        if (resid) v += resid[(size_t)(gr + j) * ldr + gc];
        if constexpr (sizeof(TOUT) == 2)
          C[(size_t)(gr + j) * ldc + gc] = __float2bfloat16(v);
        else
          C[(size_t)(gr + j) * ldc + gc] = v;
      }
    }
  }
}

// ---------------- m97-structure 128x128 GEMM (attention pieces) ----------------
// TRI_SKIP: skip tiles above the diagonal (scores). TRI_K: kmax=(by+1)*128 (PV).
template <typename TOUT, bool RELU, bool TRI_SKIP, bool TRI_K>
__global__ __launch_bounds__(256) void gemm_bt_kernel(
    const bf16* __restrict__ A, int lda, long sAb,
    const bf16* __restrict__ Bt, int ldb, long sBb,
    const float* __restrict__ bias,
    const float* __restrict__ resid, int ldr, long sRb,
    TOUT* __restrict__ C, int ldc, long sCb,
    int K, float oscale)
{
  if (TRI_SKIP && blockIdx.x > blockIdx.y) return;
  __shared__ __align__(16) bf16 As[128 * 32];
  __shared__ __align__(16) bf16 Bs[128 * 32];
  const int tid = threadIdx.x;
  const int lane = tid & 63;
  const int w = __builtin_amdgcn_readfirstlane(tid >> 6);
  const int wm = w >> 1, wn = w & 1;
  const int m0 = blockIdx.y * 128, n0 = blockIdx.x * 128;
  const bf16* Ab = A + (size_t)blockIdx.z * sAb;
  const bf16* Bb = Bt + (size_t)blockIdx.z * sBb;

  const int srow = lane >> 2;
  const int sko = (lane & 3) * 8;
  const int kmax = TRI_K ? (blockIdx.y + 1) * 128 : K;

  f32x4 acc[4][4] = {};
  for (int kt = 0; kt < kmax; kt += 32) {
    __syncthreads();
#pragma unroll
    for (int i = 0; i < 2; ++i) {
      int c = w * 2 + i;
      gload_lds16(Ab + (size_t)(m0 + c * 16 + srow) * lda + kt + sko, &As[c * 512]);
      gload_lds16(Bb + (size_t)(n0 + c * 16 + srow) * ldb + kt + sko, &Bs[c * 512]);
    }
    __syncthreads();
    const int koff = (lane >> 4) * 8;
    bf16x8 aF[4], bF[4];
#pragma unroll
    for (int m = 0; m < 4; ++m)
      aF[m] = *reinterpret_cast<const bf16x8*>(&As[(wm * 64 + m * 16 + (lane & 15)) * 32 + koff]);
#pragma unroll
    for (int n = 0; n < 4; ++n)
      bF[n] = *reinterpret_cast<const bf16x8*>(&Bs[(wn * 64 + n * 16 + (lane & 15)) * 32 + koff]);
#pragma unroll
    for (int m = 0; m < 4; ++m)
#pragma unroll
      for (int n = 0; n < 4; ++n)
        acc[m][n] = __builtin_amdgcn_mfma_f32_16x16x32_bf16(aF[m], bF[n], acc[m][n], 0, 0, 0);
  }

  const float* Rb = resid ? resid + (size_t)blockIdx.z * sRb : nullptr;
  TOUT* Cb = C + (size_t)blockIdx.z * sCb;
#pragma unroll
  for (int n = 0; n < 4; ++n) {
    int gc = n0 + wn * 64 + n * 16 + (lane & 15);
    float bv = bias ? bias[gc] : 0.0f;
#pragma unroll
    for (int m = 0; m < 4; ++m) {
      int gr = m0 + wm * 64 + m * 16 + ((lane >> 4) << 2);
#pragma unroll
      for (int j = 0; j < 4; ++j) {
        float v = acc[m][n][j] * oscale + bv;
        if (RELU) v = fmaxf(v, 0.0f);
        int row = gr + j;
        if (Rb) v += Rb[(size_t)row * ldr + gc];
        if constexpr (sizeof(TOUT) == 2)
          Cb[(size_t)row * ldc + gc] = __float2bfloat16(v);
        else
          Cb[(size_t)row * ldc + gc] = v;
      }
    }
  }
}

// ---------------- In-place causal softmax: fp32 S row -> bf16 P row ----------------
__global__ __launch_bounds__(256) void softmax_kernel(float* __restrict__ S)
{
  const int w = threadIdx.x >> 6, lane = threadIdx.x & 63;
  const int t = blockIdx.x * 4 + w;
  const int b = blockIdx.z;
  float* Srow = S + ((size_t)b * T_ + t) * T_;
  const int Keff = ((t >> 7) + 1) << 7;

  float4 vals[8];
  float mx = -1e30f;
#pragma unroll
  for (int c = 0; c < 8; ++c) {
    int col = c * 256 + lane * 4;
    if (col < Keff) {
      vals[c] = *reinterpret_cast<const float4*>(Srow + col);
#pragma unroll
      for (int j = 0; j < 4; ++j)
        if (col + j <= t) mx = fmaxf(mx, ((float*)&vals[c])[j]);
    } else {
      vals[c] = float4{0.f, 0.f, 0.f, 0.f};
    }
  }
#pragma unroll
  for (int off = 32; off > 0; off >>= 1) mx = fmaxf(mx, __shfl_xor(mx, off));

  float sum = 0.f;
#pragma unroll
  for (int c = 0; c < 8; ++c) {
    int col = c * 256 + lane * 4;
#pragma unroll
    for (int j = 0; j < 4; ++j) {
      float e = (col + j <= t) ? __expf(((float*)&vals[c])[j] - mx) : 0.f;
      ((float*)&vals[c])[j] = e;
      sum += e;
    }
  }
#pragma unroll
  for (int off = 32; off > 0; off >>= 1) sum += __shfl_xor(sum, off);
  const float inv = 1.0f / sum;

  bf16* Prow = (bf16*)Srow;
#pragma unroll
  for (int c = 0; c < 8; ++c) {
    int col = c * 256 + lane * 4;
    if (col < Keff) {
      bf16 o[4];
#pragma unroll
      for (int j = 0; j < 4; ++j) o[j] = __float2bfloat16(((float*)&vals[c])[j] * inv);
      *reinterpret_cast<ushort4*>(Prow + col) = *reinterpret_cast<ushort4*>(o);
    }
  }
}

// ---------------- launch ----------------
extern "C" void kernel_launch(void* const* d_in, const int* in_sizes, int n_in,
                              void* d_out, int out_size, void* d_ws, size_t ws_size,
                              hipStream_t stream)
{
  const float* x      = (const float*)d_in[0];
  const float* ln1_g  = (const float*)d_in[1];
  const float* ln1_b  = (const float*)d_in[2];
  const float* qkv_w  = (const float*)d_in[3];
  const float* qkv_b  = (const float*)d_in[4];
  const float* proj_w = (const float*)d_in[5];
  const float* proj_b = (const float*)d_in[6];
  const float* ln2_g  = (const float*)d_in[7];
  const float* ln2_b  = (const float*)d_in[8];
  const float* ff1_w  = (const float*)d_in[9];
  const float* ff1_b  = (const float*)d_in[10];
  const float* ff2_w  = (const float*)d_in[11];
  const float* ff2_b  = (const float*)d_in[12];
  float* out = (float*)d_out;

  // workspace layout (128 MB, liveness-planned) — same as round 4:
  //  [0,48M)   qkvb bf16        (dead after scores)  -> y [0,16M), wT [16,34M), h2 [34,50M)
  //  [48,64M)  h bf16 (LN1 out) (dead after QKV)     -> VT [48,64M) (dead after PV)
  //  [64,128M) qkv_wT [64,70M)  (dead after QKV)     -> S fp32/P bf16 -> ff1o [64,128M)
  //  x2 lives in d_out (proj writes, ff2 reads + overwrites in place)
  char* ws = (char*)d_ws;
  bf16*  qkvb    = (bf16*)(ws);
  bf16*  y       = (bf16*)(ws);
  bf16*  proj_wT = (bf16*)(ws + 16777216L);
  bf16*  ff1_wT  = (bf16*)(ws + 18874368L);
  bf16*  ff2_wT  = (bf16*)(ws + 27262976L);
  bf16*  h2      = (bf16*)(ws + 35651584L);
  bf16*  h       = (bf16*)(ws + 50331648L);
  bf16*  VT      = (bf16*)(ws + 50331648L);
  bf16*  qkv_wT  = (bf16*)(ws + 67108864L);
  float* Sbuf    = (float*)(ws + 67108864L);
  bf16*  Pbuf    = (bf16*)(ws + 67108864L);  // in-place, lda=4096
  bf16*  ff1o    = (bf16*)(ws + 67108864L);

  const int R = B_ * T_;  // 8192 rows

  // qkv_wT = bf16(qkv_w)^T
  transpose_w_kernel<<<dim3(3072 / 32, 1024 / 32), 256, 0, stream>>>(qkv_w, qkv_wT, 1024, 3072);
  // h = LN1(x)
  ln_kernel<<<dim3(R), 256, 0, stream>>>(x, ln1_g, ln1_b, h);
  // qkv = h @ qkv_w + qkv_b
  gemm256_kernel<4, bf16, false><<<dim3(3072 / 256, R / 256), 512, 0, stream>>>(
      h, D_, qkv_wT, D_, qkv_b, nullptr, 0, qkvb, 3072, D_);
  // VT = V^T per batch
  transpose_v_kernel<<<dim3(D_ / 32, T_ / 32, B_), 256, 0, stream>>>(qkvb, VT);
  // S = (Q K^T)/32, lower-triangular 128x128 tiles only, fp32
  gemm_bt_kernel<float, false, true, false><<<dim3(T_ / 128, T_ / 128, B_), 256, 0, stream>>>(
      qkvb, 3072, (long)T_ * 3072, qkvb + D_, 3072, (long)T_ * 3072,
      nullptr, nullptr, 0, 0, Sbuf, T_, (long)T_ * T_, D_, 0.03125f);
  // P = softmax(S) in place (bf16, lda=4096)
  softmax_kernel<<<dim3(T_ / 4, 1, B_), 256, 0, stream>>>(Sbuf);
  // weight transposes into dead qkvb region
  transpose_w_kernel<<<dim3(1024 / 32, 1024 / 32), 256, 0, stream>>>(proj_w, proj_wT, 1024, 1024);
  transpose_w_kernel<<<dim3(4096 / 32, 1024 / 32), 256, 0, stream>>>(ff1_w, ff1_wT, 1024, 4096);
  transpose_w_kernel<<<dim3(1024 / 32, 4096 / 32), 256, 0, stream>>>(ff2_w, ff2_wT, 4096, 1024);
  // y = P @ V   (A=P lda 4096, K capped per row-block by causality)
  gemm_bt_kernel<bf16, false, false, true><<<dim3(D_ / 128, T_ / 128, B_), 256, 0, stream>>>(
      Pbuf, 4096, (long)T_ * 4096, VT, T_, (long)D_ * T_,
      nullptr, nullptr, 0, 0, y, D_, (long)T_ * D_, T_, 1.0f);
  // x2 = x + y @ proj_w + proj_b   (into d_out)
  gemm256_kernel<2, float, false><<<dim3(D_ / 128, R / 256), 512, 0, stream>>>(
      y, D_, proj_wT, D_, proj_b, x, D_, out, D_, D_);
  // h2 = LN2(x2)
  ln_kernel<<<dim3(R), 256, 0, stream>>>(out, ln2_g, ln2_b, h2);
  // f = relu(h2 @ ff1_w + ff1_b)
  gemm256_kernel<4, bf16, true><<<dim3(F_ / 256, R / 256), 512, 0, stream>>>(
      h2, D_, ff1_wT, D_, ff1_b, nullptr, 0, ff1o, F_, D_);
  // out = x2 + f @ ff2_w + ff2_b   (in-place residual on d_out)
  gemm256_kernel<2, float, false><<<dim3(D_ / 128, R / 256), 512, 0, stream>>>(
      ff1o, F_, ff2_wT, F_, ff2_b, out, D_, out, D_, F_);
}

// Round 7
// 555.777 us; speedup vs baseline: 2.8162x; 1.0747x over previous
//
#include <hip/hip_runtime.h>
#include <hip/hip_bf16.h>

typedef __attribute__((ext_vector_type(8))) short bf16x8;
typedef __attribute__((ext_vector_type(4))) float f32x4;
using bf16 = __hip_bfloat16;

#define D_ 1024
#define T_ 2048
#define B_ 4
#define F_ 4096

__device__ __forceinline__ void gload_lds16(const void* g, void* l) {
  __builtin_amdgcn_global_load_lds(
      (const __attribute__((address_space(1))) void*)g,
      (__attribute__((address_space(3))) void*)l, 16, 0, 0);
}

// ---------------- LayerNorm (fp32 in -> bf16 out), one block per row ----------------
__global__ __launch_bounds__(256) void ln_kernel(
    const float* __restrict__ x, const float* __restrict__ g,
    const float* __restrict__ b, bf16* __restrict__ out)
{
  int row = blockIdx.x;
  int tid = threadIdx.x;
  const float4 v = *reinterpret_cast<const float4*>(x + (size_t)row * D_ + tid * 4);
  float s = v.x + v.y + v.z + v.w;
  float q = v.x * v.x + v.y * v.y + v.z * v.z + v.w * v.w;
#pragma unroll
  for (int off = 32; off > 0; off >>= 1) {
    s += __shfl_down(s, off);
    q += __shfl_down(q, off);
  }
  __shared__ float psum[4], psq[4], stats[2];
  if ((tid & 63) == 0) { psum[tid >> 6] = s; psq[tid >> 6] = q; }
  __syncthreads();
  if (tid == 0) {
    float S = psum[0] + psum[1] + psum[2] + psum[3];
    float Q = psq[0] + psq[1] + psq[2] + psq[3];
    float mu = S * (1.0f / D_);
    float var = Q * (1.0f / D_) - mu * mu;
    stats[0] = mu;
    stats[1] = rsqrtf(var + 1e-5f);
  }
  __syncthreads();
  float mu = stats[0], rv = stats[1];
  const float4 gv = *reinterpret_cast<const float4*>(g + tid * 4);
  const float4 bv = *reinterpret_cast<const float4*>(b + tid * 4);
  bf16 o[4];
  o[0] = __float2bfloat16((v.x - mu) * rv * gv.x + bv.x);
  o[1] = __float2bfloat16((v.y - mu) * rv * gv.y + bv.y);
  o[2] = __float2bfloat16((v.z - mu) * rv * gv.z + bv.z);
  o[3] = __float2bfloat16((v.w - mu) * rv * gv.w + bv.w);
  *reinterpret_cast<ushort4*>(out + (size_t)row * D_ + tid * 4) =
      *reinterpret_cast<ushort4*>(o);
}

// ---------------- Transpose fp32 [R][C] -> bf16 [C][R] ----------------
__global__ __launch_bounds__(256) void transpose_w_kernel(
    const float* __restrict__ in, bf16* __restrict__ out, int R, int C)
{
  __shared__ float t[32][33];
  int c0 = blockIdx.x * 32, r0 = blockIdx.y * 32;
  int c = threadIdx.x & 31, r8 = threadIdx.x >> 5;
#pragma unroll
  for (int i = 0; i < 4; ++i)
    t[r8 + i * 8][c] = in[(size_t)(r0 + r8 + i * 8) * C + c0 + c];
  __syncthreads();
#pragma unroll
  for (int i = 0; i < 4; ++i)
    out[(size_t)(c0 + r8 + i * 8) * R + r0 + c] = __float2bfloat16(t[c][r8 + i * 8]);
}

// ---------------- Transpose V (bf16 strided) -> VT [D][T] per batch ----------------
__global__ __launch_bounds__(256) void transpose_v_kernel(
    const bf16* __restrict__ qkv, bf16* __restrict__ vt)
{
  __shared__ bf16 t[32][34];
  int b = blockIdx.z;
  int c0 = blockIdx.x * 32;
  int r0 = blockIdx.y * 32;
  const bf16* in = qkv + (size_t)b * T_ * 3072 + 2 * D_;
  bf16* out = vt + (size_t)b * D_ * T_;
  int c = threadIdx.x & 31, r8 = threadIdx.x >> 5;
#pragma unroll
  for (int i = 0; i < 4; ++i)
    t[r8 + i * 8][c] = in[(size_t)(r0 + r8 + i * 8) * 3072 + c0 + c];
  __syncthreads();
#pragma unroll
  for (int i = 0; i < 4; ++i)
    out[(size_t)(c0 + r8 + i * 8) * T_ + r0 + c] = t[c][r8 + i * 8];
}

// ================== 8-phase 256-row GEMM (m201-style, plain HIP) ==================
// C[M,N] = A[M,K] @ Bt[N,K]^T (+bias)(+ReLU)(+fp32 resid).
// WM=128 -> 2x4 waves, BN=256, vmcnt(6).  WM=64 -> 4x2 waves, BN=128, vmcnt(4).
// LDS per buffer: A 2 halves x 128r x 128B (32KB) + B 2 halves x (BN/2)r x 128B.
// XOR swizzle ((row&7)<<4) on both sides: staging pre-swizzles global src bytes
// (gload_lds dest linear); ds_reads XOR back. Counted vmcnt at phases 4/8 only.
#define BAR_() do { asm volatile("" ::: "memory"); __builtin_amdgcn_s_barrier(); \
                    asm volatile("" ::: "memory"); } while (0)
#define LGKM0_() asm volatile("s_waitcnt lgkmcnt(0)" ::: "memory")

template <int WM, typename TOUT, bool RELU>
__global__ __launch_bounds__(512) void gemm8p_kernel(
    const bf16* __restrict__ A, int lda,
    const bf16* __restrict__ Bt, int ldb,
    const float* __restrict__ bias,
    const float* __restrict__ resid, int ldr,
    TOUT* __restrict__ C, int ldc, int K)
{
  constexpr int NW = (WM == 128) ? 4 : 2;   // waves along N
  constexpr int BN = NW * 64;
  constexpr int MF = WM / 16;               // m-frags per wave (8 or 4)
  constexpr int MQF = MF / 2;               // m-frags per quadrant
  constexpr int ABUF = 32768;               // A bytes per buffer
  constexpr int BBUF = BN * 128;            // B bytes per buffer
  constexpr int BUFSZ = ABUF + BBUF;
  constexpr int BCW = BN / 128;             // B chunks per wave per half (2 or 1)
  __shared__ __align__(16) char lds[2 * BUFSZ];

  const int tid = threadIdx.x;
  const int lane = tid & 63;
  const int w = __builtin_amdgcn_readfirstlane(tid >> 6);
  const int wm = (WM == 128) ? (w >> 2) : (w >> 1);
  const int wn = (WM == 128) ? (w & 3) : (w & 1);

  // bijective XCD swizzle (nwg % 8 == 0 for all launches here)
  const int nwg = gridDim.x * gridDim.y;
  const int flat = blockIdx.y * gridDim.x + blockIdx.x;
  const int sw = (flat & 7) * (nwg >> 3) + (flat >> 3);
  const int m0 = (sw / gridDim.x) * 256;
  const int n0 = (sw % gridDim.x) * BN;

  const int srow8 = lane >> 3;
  const int skb = ((lane & 7) ^ srow8) * 16;
  const char* Ag = (const char*)A;
  const char* Bg = (const char*)Bt;
  const long ldab = (long)lda * 2, ldbb = (long)ldb * 2;
  const int nt = K >> 6;   // K-tiles of 64 (all K here are multiples of 128)

  char* buf0 = lds;
  char* buf1 = lds + BUFSZ;

#define STAGE_A(buf, t, half)                                                     \
  do {                                                                            \
    _Pragma("unroll")                                                             \
    for (int i_ = 0; i_ < 2; ++i_) {                                              \
      int c_ = w * 2 + i_;                                                        \
      gload_lds16(Ag + (size_t)(m0 + (half)*128 + c_ * 8 + srow8) * ldab +        \
                      (long)(t)*128 + skb,                                        \
                  (buf) + (half)*16384 + c_ * 1024);                              \
    }                                                                             \
  } while (0)

#define STAGE_B(buf, t, half)                                                     \
  do {                                                                            \
    _Pragma("unroll")                                                             \
    for (int i_ = 0; i_ < BCW; ++i_) {                                            \
      int c_ = w * BCW + i_;                                                      \
      gload_lds16(Bg + (size_t)(n0 + (half) * (BN / 2) + c_ * 8 + srow8) * ldbb + \
                      (long)(t)*128 + skb,                                        \
                  (buf) + ABUF + (half) * (BBUF / 2) + c_ * 1024);                \
    }                                                                             \
  } while (0)

  const int l15 = lane & 15;
  const int kb16 = (lane >> 4) * 16;
  const int aHalf = (wm * WM) / 128;
  const int aBase = (wm * WM) % 128;
  const int bHalf = (wn * 64) / (BN / 2);
  const int bBase = (wn * 64) % (BN / 2);

#define READ_A(dst, buf, mq)                                                      \
  do {                                                                            \
    _Pragma("unroll")                                                             \
    for (int mi_ = 0; mi_ < MQF; ++mi_) {                                         \
      _Pragma("unroll")                                                           \
      for (int ks_ = 0; ks_ < 2; ++ks_) {                                         \
        int row_ = aBase + ((mq)*MQF + mi_) * 16 + l15;                           \
        dst[mi_][ks_] = *reinterpret_cast<const bf16x8*>(                         \
            (buf) + aHalf * 16384 + row_ * 128 +                                  \
            ((ks_ * 64 + kb16) ^ ((row_ & 7) << 4)));                             \
      }                                                                           \
    }                                                                             \
  } while (0)

#define READ_B(dst, buf, nq)                                                      \
  do {                                                                            \
    _Pragma("unroll")                                                             \
    for (int ni_ = 0; ni_ < 2; ++ni_) {                                           \
      _Pragma("unroll")                                                           \
      for (int ks_ = 0; ks_ < 2; ++ks_) {                                         \
        int row_ = bBase + ((nq)*2 + ni_) * 16 + l15;                             \
        dst[ni_][ks_] = *reinterpret_cast<const bf16x8*>(                         \
            (buf) + ABUF + bHalf * (BBUF / 2) + row_ * 128 +                      \
            ((ks_ * 64 + kb16) ^ ((row_ & 7) << 4)));                             \
      }                                                                           \
    }                                                                             \
  } while (0)

#define MFMA_Q(af, bf, mq, nq)                                                    \
  do {                                                                            \
    __builtin_amdgcn_s_setprio(1);                                                \
    _Pragma("unroll")                                                             \
    for (int mi_ = 0; mi_ < MQF; ++mi_) {                                         \
      _Pragma("unroll")                                                           \
      for (int ni_ = 0; ni_ < 2; ++ni_) {                                         \
        _Pragma("unroll")                                                         \
        for (int ks_ = 0; ks_ < 2; ++ks_)                                         \
          acc[(mq)*MQF + mi_][(nq)*2 + ni_] =                                     \
              __builtin_amdgcn_mfma_f32_16x16x32_bf16(                            \
                  af[mi_][ks_], bf[ni_][ks_],                                     \
                  acc[(mq)*MQF + mi_][(nq)*2 + ni_], 0, 0, 0);                    \
      }                                                                           \
    }                                                                             \
    __builtin_amdgcn_s_setprio(0);                                                \
  } while (0)

#define VM_CNT()                                                                  \
  do {                                                                            \
    if constexpr (WM == 128) asm volatile("s_waitcnt vmcnt(6)" ::: "memory");     \
    else                     asm volatile("s_waitcnt vmcnt(4)" ::: "memory");     \
  } while (0)

  f32x4 acc[MF][4] = {};
  bf16x8 aF0[MQF][2], aF1[MQF][2], bF0[2][2], bF1[2][2];

  // prologue: tile0 full, tile1 all but A-hi
  STAGE_B(buf0, 0, 0); STAGE_B(buf0, 0, 1); STAGE_A(buf0, 0, 0); STAGE_A(buf0, 0, 1);
  STAGE_B(buf1, 1, 0); STAGE_B(buf1, 1, 1); STAGE_A(buf1, 1, 0);
  VM_CNT();
  BAR_();

  for (int t0 = 0; t0 < nt; t0 += 2) {
    const int t1 = t0 + 1, t2 = t0 + 2, t3 = t0 + 3;
    const bool more = (t2 < nt);
    // p1: quad (0,0); stage A-hi(t1)
    READ_A(aF0, buf0, 0); READ_B(bF0, buf0, 0);
    STAGE_A(buf1, t1, 1);
    BAR_(); LGKM0_(); MFMA_Q(aF0, bF0, 0, 0); BAR_();
    // p2: quad (0,1)
    READ_B(bF1, buf0, 1);
    BAR_(); LGKM0_(); MFMA_Q(aF0, bF1, 0, 1); BAR_();
    // p3: quad (1,1); stage B-lo,B-hi(t2)
    READ_A(aF1, buf0, 1);
    if (more) { STAGE_B(buf0, t2, 0); STAGE_B(buf0, t2, 1); }
    BAR_(); LGKM0_(); MFMA_Q(aF1, bF1, 1, 1); BAR_();
    // p4: quad (1,0); stage A-lo(t2); counted vmcnt
    if (more) { STAGE_A(buf0, t2, 0); VM_CNT(); }
    else      { asm volatile("s_waitcnt vmcnt(0)" ::: "memory"); }
    BAR_(); MFMA_Q(aF1, bF0, 1, 0); BAR_();
    // p5: tile t1 quad (0,0); stage A-hi(t2)
    READ_A(aF0, buf1, 0); READ_B(bF0, buf1, 0);
    if (more) STAGE_A(buf0, t2, 1);
    BAR_(); LGKM0_(); MFMA_Q(aF0, bF0, 0, 0); BAR_();
    // p6: quad (0,1)
    READ_B(bF1, buf1, 1);
    BAR_(); LGKM0_(); MFMA_Q(aF0, bF1, 0, 1); BAR_();
    // p7: quad (1,1); stage B-lo,B-hi(t3)
    READ_A(aF1, buf1, 1);
    if (more) { STAGE_B(buf1, t3, 0); STAGE_B(buf1, t3, 1); }
    BAR_(); LGKM0_(); MFMA_Q(aF1, bF1, 1, 1); BAR_();
    // p8: quad (1,0); stage A-lo(t3); counted vmcnt
    if (more) { STAGE_A(buf1, t3, 0); VM_CNT(); }
    else      { asm volatile("s_waitcnt vmcnt(0)" ::: "memory"); }
    BAR_(); MFMA_Q(aF1, bF0, 1, 0); BAR_();
  }

  // epilogue
#pragma unroll
  for (int nf = 0; nf < 4; ++nf) {
    int gc = n0 + wn * 64 + nf * 16 + l15;
    float bv = bias ? bias[gc] : 0.0f;
#pragma unroll
    for (int mf = 0; mf < MF; ++mf) {
      int gr = m0 + wm * WM + mf * 16 + ((lane >> 4) << 2);
#pragma unroll
      for (int j = 0; j < 4; ++j) {
        float v = acc[mf][nf][j] + bv;
        if (RELU) v = fmaxf(v, 0.0f);
        if (resid) v += resid[(size_t)(gr + j) * ldr + gc];
        if constexpr (sizeof(TOUT) == 2)
          C[(size_t)(gr + j) * ldc + gc] = __float2bfloat16(v);
        else
          C[(size_t)(gr + j) * ldc + gc] = v;
      }
    }
  }
#undef STAGE_A
#undef STAGE_B
#undef READ_A
#undef READ_B
#undef MFMA_Q
#undef VM_CNT
}

// ---------------- m97-structure 128x128 GEMM (attention pieces) ----------------
template <typename TOUT, bool RELU, bool TRI_SKIP, bool TRI_K>
__global__ __launch_bounds__(256) void gemm_bt_kernel(
    const bf16* __restrict__ A, int lda, long sAb,
    const bf16* __restrict__ Bt, int ldb, long sBb,
    const float* __restrict__ bias,
    const float* __restrict__ resid, int ldr, long sRb,
    TOUT* __restrict__ C, int ldc, long sCb,
    int K, float oscale)
{
  if (TRI_SKIP && blockIdx.x > blockIdx.y) return;
  __shared__ __align__(16) bf16 As[128 * 32];
  __shared__ __align__(16) bf16 Bs[128 * 32];
  const int tid = threadIdx.x;
  const int lane = tid & 63;
  const int w = __builtin_amdgcn_readfirstlane(tid >> 6);
  const int wm = w >> 1, wn = w & 1;
  const int m0 = blockIdx.y * 128, n0 = blockIdx.x * 128;
  const bf16* Ab = A + (size_t)blockIdx.z * sAb;
  const bf16* Bb = Bt + (size_t)blockIdx.z * sBb;

  const int srow = lane >> 2;
  const int sko = (lane & 3) * 8;
  const int kmax = TRI_K ? (blockIdx.y + 1) * 128 : K;

  f32x4 acc[4][4] = {};
  for (int kt = 0; kt < kmax; kt += 32) {
    __syncthreads();
#pragma unroll
    for (int i = 0; i < 2; ++i) {
      int c = w * 2 + i;
      gload_lds16(Ab + (size_t)(m0 + c * 16 + srow) * lda + kt + sko, &As[c * 512]);
      gload_lds16(Bb + (size_t)(n0 + c * 16 + srow) * ldb + kt + sko, &Bs[c * 512]);
    }
    __syncthreads();
    const int koff = (lane >> 4) * 8;
    bf16x8 aF[4], bF[4];
#pragma unroll
    for (int m = 0; m < 4; ++m)
      aF[m] = *reinterpret_cast<const bf16x8*>(&As[(wm * 64 + m * 16 + (lane & 15)) * 32 + koff]);
#pragma unroll
    for (int n = 0; n < 4; ++n)
      bF[n] = *reinterpret_cast<const bf16x8*>(&Bs[(wn * 64 + n * 16 + (lane & 15)) * 32 + koff]);
#pragma unroll
    for (int m = 0; m < 4; ++m)
#pragma unroll
      for (int n = 0; n < 4; ++n)
        acc[m][n] = __builtin_amdgcn_mfma_f32_16x16x32_bf16(aF[m], bF[n], acc[m][n], 0, 0, 0);
  }

  const float* Rb = resid ? resid + (size_t)blockIdx.z * sRb : nullptr;
  TOUT* Cb = C + (size_t)blockIdx.z * sCb;
#pragma unroll
  for (int n = 0; n < 4; ++n) {
    int gc = n0 + wn * 64 + n * 16 + (lane & 15);
    float bv = bias ? bias[gc] : 0.0f;
#pragma unroll
    for (int m = 0; m < 4; ++m) {
      int gr = m0 + wm * 64 + m * 16 + ((lane >> 4) << 2);
#pragma unroll
      for (int j = 0; j < 4; ++j) {
        float v = acc[m][n][j] * oscale + bv;
        if (RELU) v = fmaxf(v, 0.0f);
        int row = gr + j;
        if (Rb) v += Rb[(size_t)row * ldr + gc];
        if constexpr (sizeof(TOUT) == 2)
          Cb[(size_t)row * ldc + gc] = __float2bfloat16(v);
        else
          Cb[(size_t)row * ldc + gc] = v;
      }
    }
  }
}

// ---------------- In-place causal softmax: fp32 S row -> bf16 P row ----------------
__global__ __launch_bounds__(256) void softmax_kernel(float* __restrict__ S)
{
  const int w = threadIdx.x >> 6, lane = threadIdx.x & 63;
  const int t = blockIdx.x * 4 + w;
  const int b = blockIdx.z;
  float* Srow = S + ((size_t)b * T_ + t) * T_;
  const int Keff = ((t >> 7) + 1) << 7;

  float4 vals[8];
  float mx = -1e30f;
#pragma unroll
  for (int c = 0; c < 8; ++c) {
    int col = c * 256 + lane * 4;
    if (col < Keff) {
      vals[c] = *reinterpret_cast<const float4*>(Srow + col);
#pragma unroll
      for (int j = 0; j < 4; ++j)
        if (col + j <= t) mx = fmaxf(mx, ((float*)&vals[c])[j]);
    } else {
      vals[c] = float4{0.f, 0.f, 0.f, 0.f};
    }
  }
#pragma unroll
  for (int off = 32; off > 0; off >>= 1) mx = fmaxf(mx, __shfl_xor(mx, off));

  float sum = 0.f;
#pragma unroll
  for (int c = 0; c < 8; ++c) {
    int col = c * 256 + lane * 4;
#pragma unroll
    for (int j = 0; j < 4; ++j) {
      float e = (col + j <= t) ? __expf(((float*)&vals[c])[j] - mx) : 0.f;
      ((float*)&vals[c])[j] = e;
      sum += e;
    }
  }
#pragma unroll
  for (int off = 32; off > 0; off >>= 1) sum += __shfl_xor(sum, off);
  const float inv = 1.0f / sum;

  bf16* Prow = (bf16*)Srow;
#pragma unroll
  for (int c = 0; c < 8; ++c) {
    int col = c * 256 + lane * 4;
    if (col < Keff) {
      bf16 o[4];
#pragma unroll
      for (int j = 0; j < 4; ++j) o[j] = __float2bfloat16(((float*)&vals[c])[j] * inv);
      *reinterpret_cast<ushort4*>(Prow + col) = *reinterpret_cast<ushort4*>(o);
    }
  }
}

// ---------------- launch ----------------
extern "C" void kernel_launch(void* const* d_in, const int* in_sizes, int n_in,
                              void* d_out, int out_size, void* d_ws, size_t ws_size,
                              hipStream_t stream)
{
  const float* x      = (const float*)d_in[0];
  const float* ln1_g  = (const float*)d_in[1];
  const float* ln1_b  = (const float*)d_in[2];
  const float* qkv_w  = (const float*)d_in[3];
  const float* qkv_b  = (const float*)d_in[4];
  const float* proj_w = (const float*)d_in[5];
  const float* proj_b = (const float*)d_in[6];
  const float* ln2_g  = (const float*)d_in[7];
  const float* ln2_b  = (const float*)d_in[8];
  const float* ff1_w  = (const float*)d_in[9];
  const float* ff1_b  = (const float*)d_in[10];
  const float* ff2_w  = (const float*)d_in[11];
  const float* ff2_b  = (const float*)d_in[12];
  float* out = (float*)d_out;

  // workspace layout (128 MB, liveness-planned):
  //  [0,48M)   qkvb bf16        (dead after scores)  -> y [0,16M), wT [16,34M), h2 [34,50M)
  //  [48,64M)  h bf16 (LN1 out) (dead after QKV)     -> VT [48,64M) (dead after PV)
  //  [64,128M) qkv_wT [64,70M)  (dead after QKV)     -> S fp32/P bf16 -> ff1o [64,128M)
  //  x2 lives in d_out (proj writes, ff2 reads + overwrites in place)
  char* ws = (char*)d_ws;
  bf16*  qkvb    = (bf16*)(ws);
  bf16*  y       = (bf16*)(ws);
  bf16*  proj_wT = (bf16*)(ws + 16777216L);
  bf16*  ff1_wT  = (bf16*)(ws + 18874368L);
  bf16*  ff2_wT  = (bf16*)(ws + 27262976L);
  bf16*  h2      = (bf16*)(ws + 35651584L);
  bf16*  h       = (bf16*)(ws + 50331648L);
  bf16*  VT      = (bf16*)(ws + 50331648L);
  bf16*  qkv_wT  = (bf16*)(ws + 67108864L);
  float* Sbuf    = (float*)(ws + 67108864L);
  bf16*  Pbuf    = (bf16*)(ws + 67108864L);  // in-place, lda=4096
  bf16*  ff1o    = (bf16*)(ws + 67108864L);

  const int R = B_ * T_;  // 8192 rows

  // qkv_wT = bf16(qkv_w)^T
  transpose_w_kernel<<<dim3(3072 / 32, 1024 / 32), 256, 0, stream>>>(qkv_w, qkv_wT, 1024, 3072);
  // h = LN1(x)
  ln_kernel<<<dim3(R), 256, 0, stream>>>(x, ln1_g, ln1_b, h);
  // qkv = h @ qkv_w + qkv_b   (grid 12x32 = 384 blocks)
  gemm8p_kernel<128, bf16, false><<<dim3(3072 / 256, R / 256), 512, 0, stream>>>(
      h, D_, qkv_wT, D_, qkv_b, nullptr, 0, qkvb, 3072, D_);
  // VT = V^T per batch
  transpose_v_kernel<<<dim3(D_ / 32, T_ / 32, B_), 256, 0, stream>>>(qkvb, VT);
  // S = (Q K^T)/32, lower-triangular 128x128 tiles only, fp32
  gemm_bt_kernel<float, false, true, false><<<dim3(T_ / 128, T_ / 128, B_), 256, 0, stream>>>(
      qkvb, 3072, (long)T_ * 3072, qkvb + D_, 3072, (long)T_ * 3072,
      nullptr, nullptr, 0, 0, Sbuf, T_, (long)T_ * T_, D_, 0.03125f);
  // P = softmax(S) in place (bf16, lda=4096)
  softmax_kernel<<<dim3(T_ / 4, 1, B_), 256, 0, stream>>>(Sbuf);
  // weight transposes into dead qkvb region
  transpose_w_kernel<<<dim3(1024 / 32, 1024 / 32), 256, 0, stream>>>(proj_w, proj_wT, 1024, 1024);
  transpose_w_kernel<<<dim3(4096 / 32, 1024 / 32), 256, 0, stream>>>(ff1_w, ff1_wT, 1024, 4096);
  transpose_w_kernel<<<dim3(1024 / 32, 4096 / 32), 256, 0, stream>>>(ff2_w, ff2_wT, 4096, 1024);
  // y = P @ V   (A=P lda 4096, K capped per row-block by causality)
  gemm_bt_kernel<bf16, false, false, true><<<dim3(D_ / 128, T_ / 128, B_), 256, 0, stream>>>(
      Pbuf, 4096, (long)T_ * 4096, VT, T_, (long)D_ * T_,
      nullptr, nullptr, 0, 0, y, D_, (long)T_ * D_, T_, 1.0f);
  // x2 = x + y @ proj_w + proj_b   (into d_out; grid 8x32 = 256 blocks)
  gemm8p_kernel<64, float, false><<<dim3(D_ / 128, R / 256), 512, 0, stream>>>(
      y, D_, proj_wT, D_, proj_b, x, D_, out, D_, D_);
  // h2 = LN2(x2)
  ln_kernel<<<dim3(R), 256, 0, stream>>>(out, ln2_g, ln2_b, h2);
  // f = relu(h2 @ ff1_w + ff1_b)   (grid 16x32 = 512 blocks)
  gemm8p_kernel<128, bf16, true><<<dim3(F_ / 256, R / 256), 512, 0, stream>>>(
      h2, D_, ff1_wT, D_, ff1_b, nullptr, 0, ff1o, F_, D_);
  // out = x2 + f @ ff2_w + ff2_b   (in-place residual on d_out; 256 blocks)
  gemm8p_kernel<64, float, false><<<dim3(D_ / 128, R / 256), 512, 0, stream>>>(
      ff1o, F_, ff2_wT, F_, ff2_b, out, D_, out, D_, F_);
}